// Round 2
// baseline (162.558 us; speedup 1.0000x reference)
//
#include <hip/hip_runtime.h>
#include <hip/hip_bf16.h>

// SimpleRNN(tanh) + Dense(5) + softmax, fused. B=8192, T=187, D=1, H=128, C=5.
//
// R2 design: ONE WAVE owns the full hidden dim (128 j) for a 16-batch tile.
// Transposed recurrence h_pre^T = U^T h^T via mfma_f32_16x16x32_f16:
//   - 8 j-tiles x 4 K-tiles = 32 MFMA/step, 8 independent depth-4 chains
//   - D-fragment layout == next step's B-fragment layout (in-lane), so the
//     recurrence never leaves registers: no LDS, no barriers.
//   - fp16 operands (not bf16): 8x lower quantization error for both U and h,
//     so no hi/lo error-split is needed (halves MFMA work vs R1).
// Head (logits + softmax) done in-wave with 2 shfl_xor butterflies.

#define BT 8192
#define TS 187
#define HD 128
#define NC 5

typedef float    f32x4 __attribute__((ext_vector_type(4)));
typedef _Float16 f16x8 __attribute__((ext_vector_type(8)));

__device__ __forceinline__ float tanh_fast(float v) {
    // tanh(v) = 1 - 2/(exp(2v)+1); exact at +-inf, no NaN (rcp(inf)=0).
    float e = __expf(2.0f * v);
    float r = __builtin_amdgcn_rcpf(e + 1.0f);
    return fmaf(-2.0f, r, 1.0f);
}

__global__ __launch_bounds__(64, 1)
void rnn_fused(const float* __restrict__ xg, const float* __restrict__ wg,
               const float* __restrict__ ug, const float* __restrict__ bg,
               const float* __restrict__ wdg, const float* __restrict__ bdg,
               float* __restrict__ outg)
{
    const int lane = threadIdx.x;       // 0..63 (one wave per block)
    const int l15  = lane & 15;         // batch col within tile / j col for A
    const int l4   = lane >> 4;         // 0..3
    const int b0   = blockIdx.x * 16;   // batch group

    // ---- U^T fragments in fp16. A-frag (M=j, K=i):
    //   m = l15 -> j = 16*jt + l15 ; elem e -> i = 32*T + 16*(e>>2) + 4*l4 + (e&3)
    f16x8 uf[8][4];
    #pragma unroll
    for (int jt = 0; jt < 8; ++jt) {
        const int j = 16*jt + l15;
        #pragma unroll
        for (int T = 0; T < 4; ++T) {
            #pragma unroll
            for (int e = 0; e < 8; ++e) {
                const int i = 32*T + 16*(e>>2) + 4*l4 + (e&3);
                uf[jt][T][e] = (_Float16)ug[i*HD + j];
            }
        }
    }

    // ---- per-lane W, b (rows j = 16*jt + 4*l4 + q, matching D-frag layout)
    float wv[8][4], bv[8][4];
    #pragma unroll
    for (int jt = 0; jt < 8; ++jt)
        #pragma unroll
        for (int q = 0; q < 4; ++q) {
            const int j = 16*jt + 4*l4 + q;
            wv[jt][q] = wg[j];
            bv[jt][q] = bg[j];
        }

    // ---- state: h fragments (B-operand layout), h0 = 0
    f16x8 hfr[4];
    #pragma unroll
    for (int T = 0; T < 4; ++T)
        #pragma unroll
        for (int e = 0; e < 8; ++e) hfr[T][e] = (_Float16)0.0f;

    const float* xrow = xg + (long)(b0 + l15) * TS;
    float xv = xrow[0];

    f32x4 acc[8];   // post-tanh h lives here after the last step

    for (int s = 0; s < TS; ++s) {
        const int sn = (s + 1 < TS) ? s + 1 : TS - 1;
        float xnext = xrow[sn];                    // prefetch, hidden under MFMAs

        // fp32 init: x*W + b
        #pragma unroll
        for (int jt = 0; jt < 8; ++jt)
            #pragma unroll
            for (int q = 0; q < 4; ++q)
                acc[jt][q] = fmaf(xv, wv[jt][q], bv[jt][q]);

        // h_pre^T += U^T h^T  (T-outer: consecutive MFMAs independent)
        #pragma unroll
        for (int T = 0; T < 4; ++T)
            #pragma unroll
            for (int jt = 0; jt < 8; ++jt)
                acc[jt] = __builtin_amdgcn_mfma_f32_16x16x32_f16(uf[jt][T], hfr[T], acc[jt], 0, 0, 0);

        // tanh in place
        #pragma unroll
        for (int jt = 0; jt < 8; ++jt)
            #pragma unroll
            for (int q = 0; q < 4; ++q)
                acc[jt][q] = tanh_fast(acc[jt][q]);

        // D-frag -> next B-frag: hfr[T] = [acc[2T][0..3] | acc[2T+1][0..3]] in fp16
        #pragma unroll
        for (int T = 0; T < 4; ++T)
            #pragma unroll
            for (int e = 0; e < 8; ++e)
                hfr[T][e] = (_Float16)((e < 4) ? acc[2*T][e] : acc[2*T + 1][e - 4]);

        xv = xnext;
    }

    // ---- head: logits = h @ Wd + bd, in-wave reduce over l4 groups ----
    float p[NC];
    #pragma unroll
    for (int c = 0; c < NC; ++c) p[c] = bdg[c];
    #pragma unroll
    for (int jt = 0; jt < 8; ++jt)
        #pragma unroll
        for (int q = 0; q < 4; ++q) {
            const float h = acc[jt][q];
            const int   j = 16*jt + 4*l4 + q;
            #pragma unroll
            for (int c = 0; c < NC; ++c)
                p[c] = fmaf(h, wdg[j*NC + c], p[c]);
        }
    #pragma unroll
    for (int c = 0; c < NC; ++c) {
        p[c] += __shfl_xor(p[c], 16, 64);
        p[c] += __shfl_xor(p[c], 32, 64);
    }

    // softmax over 5, one writer lane per batch row
    float m = p[0];
    #pragma unroll
    for (int c = 1; c < NC; ++c) m = fmaxf(m, p[c]);
    float e[NC], ssum = 0.0f;
    #pragma unroll
    for (int c = 0; c < NC; ++c) { e[c] = __expf(p[c] - m); ssum += e[c]; }
    const float rs = 1.0f / ssum;
    if (l4 == 0) {
        #pragma unroll
        for (int c = 0; c < NC; ++c)
            outg[(long)(b0 + l15)*NC + c] = e[c] * rs;
    }
}

extern "C" void kernel_launch(void* const* d_in, const int* in_sizes, int n_in,
                              void* d_out, int out_size, void* d_ws, size_t ws_size,
                              hipStream_t stream) {
    const float* x  = (const float*)d_in[0];  // [8192][187][1]
    const float* W  = (const float*)d_in[1];  // [1][128]
    const float* U  = (const float*)d_in[2];  // [128][128]
    const float* b  = (const float*)d_in[3];  // [128]
    const float* Wd = (const float*)d_in[4];  // [128][5]
    const float* bd = (const float*)d_in[5];  // [5]
    float* out = (float*)d_out;               // [8192][5]

    rnn_fused<<<BT / 16, 64, 0, stream>>>(x, W, U, b, Wd, bd, out);
}